// Round 3
// baseline (23859.834 us; speedup 1.0000x reference)
//
#include <hip/hip_runtime.h>
#include <hip/hip_fp16.h>

// LSTM (2-layer bidirectional, B=64 T=1024 I=H=256) for MI355X.
// R3: register/AGPR-resident W_hh (as R2) + Infinity-Cache-direct h exchange.
// All cross-WG communication uses relaxed SYSTEM-scope accesses (sc0 sc1 bits:
// bypass L1/L2, served by the device-coherent IC) -> NO buffer_inv / buffer_wbl2
// per step (R2's 7 us/step overhead). xg is stored by gemm_xg in a permuted
// layout so each (WG,step) reads one contiguous 32KB block with 8B loads.
// d_out = o2 [B,T,512] fp32 ++ h_n [4,B,H] ++ c_n [4,B,H].

#define BQ 64
#define TT 1024
#define II 256
#define M0 (BQ * TT)  // 65536
#define G4 4          // WGs per direction (hidden slices of 64)

typedef _Float16 half8 __attribute__((ext_vector_type(8)));
typedef _Float16 half4 __attribute__((ext_vector_type(4)));
typedef float floatx4 __attribute__((ext_vector_type(4)));
typedef unsigned long long u64;

__device__ __forceinline__ float fsig(float x) {
  float e = __builtin_amdgcn_exp2f(-1.44269504089f * x);
  return __builtin_amdgcn_rcpf(1.0f + e);
}
__device__ __forceinline__ float ftanh(float x) {
  float ax = __builtin_fabsf(x);
  float e = __builtin_amdgcn_exp2f(-2.88539008178f * ax);
  float r = (1.0f - e) * __builtin_amdgcn_rcpf(1.0f + e);
  return __builtin_copysignf(r, x);
}
__device__ __forceinline__ half8 cvt8(float4 a, float4 b) {
  half8 h;
  h[0] = (_Float16)a.x; h[1] = (_Float16)a.y; h[2] = (_Float16)a.z; h[3] = (_Float16)a.w;
  h[4] = (_Float16)b.x; h[5] = (_Float16)b.y; h[6] = (_Float16)b.z; h[7] = (_Float16)b.w;
  return h;
}
__device__ __forceinline__ half8 h8_from(u64 lo, u64 hi) {
  union { u64 u[2]; half8 v; } cv; cv.u[0] = lo; cv.u[1] = hi; return cv.v;
}

// x [B,T,I] fp32 -> xT [(t*B+b), I] f16
__global__ __launch_bounds__(256) void pack_xT(const float* __restrict__ x,
                                               _Float16* __restrict__ xT) {
  int gid = blockIdx.x * 256 + threadIdx.x;  // one thread per 8 elems
  int chunk = gid & 31;
  int row = gid >> 5;  // row = t*64 + b
  int t = row >> 6, b = row & 63;
  const float* src = x + ((size_t)b * TT + t) * II + chunk * 8;
  float4 v0 = *(const float4*)src;
  float4 v1 = *(const float4*)(src + 4);
  *(half8*)(xT + (size_t)row * II + chunk * 8) = cvt8(v0, v1);
}

// W fp32 [D][1024][K] -> f16 B-fragment layout [d][tile][ks][lane][8]
// fragment: n = tile*16 + (lane&15), k = ks*32 + (lane>>4)*8 + j
__global__ __launch_bounds__(256) void pack_B(const float* __restrict__ W,
                                              _Float16* __restrict__ dst, int K,
                                              int total) {
  int gid = blockIdx.x * 256 + threadIdx.x;
  if (gid >= total) return;
  int per = 64 * (K / 32) * 64;  // threads per dir
  int d = gid / per;
  int i = gid - d * per;
  int lane = i & 63;
  int i2 = i >> 6;  // tile*(K/32) + ks
  int n = (i2 / (K / 32)) * 16 + (lane & 15);
  int k = (i2 % (K / 32)) * 32 + (lane >> 4) * 8;
  const float* s = W + ((size_t)d * 1024 + n) * K + k;
  float4 v0 = *(const float4*)s;
  float4 v1 = *(const float4*)(s + 4);
  *(half8*)(dst + (size_t)gid * 8) = cvt8(v0, v1);
}

__global__ __launch_bounds__(256) void add_bias(const float* __restrict__ a,
                                                const float* __restrict__ b,
                                                float* __restrict__ o, int n) {
  int i = blockIdx.x * 256 + threadIdx.x;
  if (i < n) o[i] = a[i] + b[i];
}

// xg2 layout: element ((((d*1024+tt)*4 + s)*64 + b)*64 + jj)*4 + g
// (per (d,tt,s): contiguous 32KB block; per (b,jj): 4 gates = 8B)
// out[d][m][n] = sum_k A[m][k]*W[d][n][k] + bias[d][n]. M=65536, N=1024.
template <int K>
__global__ __launch_bounds__(256) void gemm_xg(const _Float16* __restrict__ A,
                                               const _Float16* __restrict__ Bp,
                                               const float* __restrict__ bias,
                                               _Float16* __restrict__ xg2) {
  const int d = blockIdx.z;
  const int n0 = blockIdx.x * 128;
  const int m0 = blockIdx.y * 128;
  const int tid = threadIdx.x;
  const int lane = tid & 63, wave = tid >> 6;
  const int wr = wave >> 1, wc = wave & 1;
  const int cl = lane & 15, lh = lane >> 4;
  __shared__ _Float16 As[128][48];  // pad 32->48
  const _Float16* Bb = Bp + (size_t)d * (1024 * K);
  floatx4 acc[4][4];
#pragma unroll
  for (int i = 0; i < 4; i++)
#pragma unroll
    for (int j = 0; j < 4; j++) acc[i][j] = (floatx4){0.f, 0.f, 0.f, 0.f};

  for (int ks = 0; ks < K / 32; ++ks) {
#pragma unroll
    for (int it = 0; it < 2; ++it) {  // stage A tile 128x32 f16
      int row = it * 64 + (tid >> 2);
      int col = (tid & 3) * 8;
      *(half8*)(&As[row][col]) =
          *(const half8*)(A + (size_t)(m0 + row) * K + ks * 32 + col);
    }
    __syncthreads();
    half8 a[4], b[4];
#pragma unroll
    for (int rt = 0; rt < 4; rt++)
      a[rt] = *(const half8*)(&As[wr * 64 + rt * 16 + cl][lh * 8]);
#pragma unroll
    for (int ct = 0; ct < 4; ct++) {
      int tile = (n0 >> 4) + wc * 4 + ct;
      b[ct] = *(const half8*)(Bb + ((size_t)(tile * (K / 32) + ks) * 64 + lane) * 8);
    }
#pragma unroll
    for (int rt = 0; rt < 4; rt++)
#pragma unroll
      for (int ct = 0; ct < 4; ct++)
        acc[rt][ct] = __builtin_amdgcn_mfma_f32_16x16x32_f16(a[rt], b[ct], acc[rt][ct], 0, 0, 0);
    __syncthreads();
  }
#pragma unroll
  for (int ct = 0; ct < 4; ct++) {
    int n = n0 + wc * 64 + ct * 16 + cl;
    int g = n >> 8, sl = (n >> 6) & 3, jj = n & 63;
    float bv = bias[d * 1024 + n];
#pragma unroll
    for (int rt = 0; rt < 4; rt++) {
#pragma unroll
      for (int r = 0; r < 4; r++) {
        int m = m0 + wr * 64 + rt * 16 + lh * 4 + r;
        int ttv = m >> 6, b = m & 63;
        xg2[((((size_t)d * 1024 + ttv) * 4 + sl) * 64 + b) * 256 + jj * 4 + g] =
            (_Float16)(acc[rt][ct][r] + bv);
      }
    }
  }
}

// Persistent recurrence, register-resident weights, IC-direct h exchange.
// 8 WGs: dir = wg>>2, hidden-slice s = wg&3 (64 hidden each).
// 8 waves as 2M x 4N: wr = wave>>2 (batch half), wc = wave&3 (16-hidden col).
// Lane holds i,f,g,o for ONE hidden index j. c in regs.
template <int LAYER>
__global__ __launch_bounds__(512, 2) void lstm_rec(
    const _Float16* __restrict__ xg2, const _Float16* __restrict__ Whp,
    _Float16* __restrict__ o1, float* __restrict__ out,
    _Float16* __restrict__ hx, unsigned* __restrict__ ctr) {
  const int wg = blockIdx.x;
  const int dir = wg >> 2, s = wg & 3;
  const int tid = threadIdx.x;
  const int lane = tid & 63, wave = tid >> 6;
  const int cl = lane & 15, lh = lane >> 4;
  const int wr = wave >> 2, wc = wave & 3;
  const int jj = wc * 16 + cl;  // hidden within slice
  const int j = s * 64 + jj;    // hidden 0..255
  const int pair = LAYER * 2 + dir;
  unsigned* myctr = ctr + pair * 64;  // 256B apart: no false sharing in IC
  _Float16* buf0 = hx + (size_t)(pair * 2 + 0) * (64 * 256);
  _Float16* buf1 = hx + (size_t)(pair * 2 + 1) * (64 * 256);
  const size_t o2elems = (size_t)BQ * TT * 512;

  // W fragments once: w[g][ks], tile = g*16 + s*4 + wc (-> AGPRs, 128 regs).
  const _Float16* Wb = Whp + (size_t)dir * (1024 * 256);
  half8 w[4][8];
#pragma unroll
  for (int g = 0; g < 4; g++) {
    const int tile = g * 16 + s * 4 + wc;
#pragma unroll
    for (int ks = 0; ks < 8; ks++)
      w[g][ks] = *(const half8*)(Wb + ((size_t)(tile * 8 + ks) * 64 + lane) * 8);
  }
  float c[2][4];
#pragma unroll
  for (int mi = 0; mi < 2; mi++)
#pragma unroll
    for (int r = 0; r < 4; r++) c[mi][r] = 0.f;

  for (int t = 0; t < TT; ++t) {
    const int tt = dir ? (TT - 1 - t) : t;
    // xg prefetch: contiguous 32KB block, 8B/thread-load (4 gates per (b,jj)).
    const _Float16* xb = xg2 + ((((size_t)dir * TT + tt) * 4 + s) << 14);
    u64 xraw[2][4];
#pragma unroll
    for (int mi = 0; mi < 2; mi++)
#pragma unroll
      for (int r = 0; r < 4; r++) {
        int b = wr * 32 + mi * 16 + lh * 4 + r;
        xraw[mi][r] = *(const u64*)(xb + ((size_t)b * 64 + jj) * 4);
      }

    // Wait: all 4 WGs of this dir committed step t-1 (h_t ready in IC; also
    // proves buf[(t+1)&1] fully consumed, safe to overwrite below).
    if (tid == 0) {
      const unsigned target = (unsigned)(G4 * t);
      while (__hip_atomic_load(myctr, __ATOMIC_RELAXED,
                               __HIP_MEMORY_SCOPE_SYSTEM) < target) {
        __builtin_amdgcn_s_sleep(1);
      }
    }
    __syncthreads();

    const _Float16* hr = (t & 1) ? buf1 : buf0;
    floatx4 acc[2][4];
#pragma unroll
    for (int mi = 0; mi < 2; mi++)
#pragma unroll
      for (int g = 0; g < 4; g++) acc[mi][g] = (floatx4){0.f, 0.f, 0.f, 0.f};
#pragma unroll
    for (int ks = 0; ks < 8; ks++) {
      // A-fragment row = cl (batch), k = ks*32 + lh*8 + e; IC-direct 8B loads.
      const _Float16* p0 = hr + (size_t)(wr * 32 + cl) * 256 + ks * 32 + lh * 8;
      const _Float16* p1 = hr + (size_t)(wr * 32 + 16 + cl) * 256 + ks * 32 + lh * 8;
      u64 a0l = __hip_atomic_load((const u64*)p0, __ATOMIC_RELAXED, __HIP_MEMORY_SCOPE_SYSTEM);
      u64 a0h = __hip_atomic_load((const u64*)(p0 + 4), __ATOMIC_RELAXED, __HIP_MEMORY_SCOPE_SYSTEM);
      u64 a1l = __hip_atomic_load((const u64*)p1, __ATOMIC_RELAXED, __HIP_MEMORY_SCOPE_SYSTEM);
      u64 a1h = __hip_atomic_load((const u64*)(p1 + 4), __ATOMIC_RELAXED, __HIP_MEMORY_SCOPE_SYSTEM);
      half8 a0 = h8_from(a0l, a0h), a1 = h8_from(a1l, a1h);
#pragma unroll
      for (int g = 0; g < 4; g++) {
        acc[0][g] = __builtin_amdgcn_mfma_f32_16x16x32_f16(a0, w[g][ks], acc[0][g], 0, 0, 0);
        acc[1][g] = __builtin_amdgcn_mfma_f32_16x16x32_f16(a1, w[g][ks], acc[1][g], 0, 0, 0);
      }
    }

    _Float16* hw = (t & 1) ? buf0 : buf1;
#pragma unroll
    for (int mi = 0; mi < 2; mi++)
#pragma unroll
      for (int r = 0; r < 4; r++) {
        union { u64 u; half4 h; } xc; xc.u = xraw[mi][r];
        float gi = acc[mi][0][r] + (float)xc.h[0];
        float gf = acc[mi][1][r] + (float)xc.h[1];
        float gg = acc[mi][2][r] + (float)xc.h[2];
        float go = acc[mi][3][r] + (float)xc.h[3];
        float cc = fsig(gf) * c[mi][r] + fsig(gi) * ftanh(gg);
        c[mi][r] = cc;
        float h = fsig(go) * ftanh(cc);
        const int b = wr * 32 + mi * 16 + lh * 4 + r;
        __hip_atomic_store(hw + (size_t)b * 256 + j, (_Float16)h,
                           __ATOMIC_RELAXED, __HIP_MEMORY_SCOPE_SYSTEM);
        if (LAYER == 0) {
          __builtin_nontemporal_store((_Float16)h,
              o1 + ((size_t)tt * BQ + b) * 512 + dir * 256 + j);
        } else {
          __builtin_nontemporal_store(h,
              out + ((size_t)b * TT + tt) * 512 + dir * 256 + j);
        }
        if (t == TT - 1) {
          const int row = LAYER * 2 + dir;
          out[o2elems + ((size_t)row * BQ + b) * 256 + j] = h;
          out[o2elems + (size_t)4 * BQ * 256 + ((size_t)row * BQ + b) * 256 + j] = cc;
        }
      }

    __syncthreads();  // drains vmcnt(0): h stores ack'd at IC before signal
    if (tid == 0)
      __hip_atomic_fetch_add(myctr, 1u, __ATOMIC_RELAXED, __HIP_MEMORY_SCOPE_SYSTEM);
  }
}

extern "C" void kernel_launch(void* const* d_in, const int* in_sizes, int n_in,
                              void* d_out, int out_size, void* d_ws, size_t ws_size,
                              hipStream_t stream) {
  (void)in_sizes; (void)n_in; (void)out_size; (void)ws_size;
  const float* x = (const float*)d_in[0];
  // d_in[1] = hidden_state, ignored by the module
  const float* wih0 = (const float*)d_in[2];
  const float* whh0 = (const float*)d_in[3];
  const float* bih0 = (const float*)d_in[4];
  const float* bhh0 = (const float*)d_in[5];
  const float* wih1 = (const float*)d_in[6];
  const float* whh1 = (const float*)d_in[7];
  const float* bih1 = (const float*)d_in[8];
  const float* bhh1 = (const float*)d_in[9];
  float* out = (float*)d_out;

  char* p = (char*)d_ws;
  unsigned* ctr = (unsigned*)p;   p += 1024;                          // 4 ctrs, 256B apart
  _Float16* hx = (_Float16*)p;    p += (size_t)4 * 2 * 64 * 256 * 2;  // 256 KB exchange
  _Float16* xT = (_Float16*)p;    p += (size_t)M0 * II * 2;           // 32 MB
  _Float16* o1 = (_Float16*)p;    p += (size_t)M0 * 512 * 2;          // 64 MB
  _Float16* xgb = (_Float16*)p;   p += (size_t)2 * M0 * 1024 * 2;     // 256 MB
  _Float16* pwih0 = (_Float16*)p; p += (size_t)2 * 1024 * 256 * 2;
  _Float16* pwhh0 = (_Float16*)p; p += (size_t)2 * 1024 * 256 * 2;
  _Float16* pwih1 = (_Float16*)p; p += (size_t)2 * 1024 * 512 * 2;
  _Float16* pwhh1 = (_Float16*)p; p += (size_t)2 * 1024 * 256 * 2;
  float* bias0 = (float*)p;       p += 2 * 1024 * 4;
  float* bias1 = (float*)p;       p += 2 * 1024 * 4;

  // zero counters + h exchange (d_ws is re-poisoned 0xAA before every replay)
  hipMemsetAsync(d_ws, 0, 1024 + (size_t)4 * 2 * 64 * 256 * 2, stream);

  hipLaunchKernelGGL(pack_xT, dim3(8192), dim3(256), 0, stream, x, xT);
  hipLaunchKernelGGL(pack_B, dim3(256), dim3(256), 0, stream, wih0, pwih0, 256, 2 * 1024 * 256 / 8);
  hipLaunchKernelGGL(pack_B, dim3(256), dim3(256), 0, stream, whh0, pwhh0, 256, 2 * 1024 * 256 / 8);
  hipLaunchKernelGGL(pack_B, dim3(512), dim3(256), 0, stream, wih1, pwih1, 512, 2 * 1024 * 512 / 8);
  hipLaunchKernelGGL(pack_B, dim3(256), dim3(256), 0, stream, whh1, pwhh1, 256, 2 * 1024 * 256 / 8);
  hipLaunchKernelGGL(add_bias, dim3(8), dim3(256), 0, stream, bih0, bhh0, bias0, 2048);
  hipLaunchKernelGGL(add_bias, dim3(8), dim3(256), 0, stream, bih1, bhh1, bias1, 2048);

  hipLaunchKernelGGL((gemm_xg<256>), dim3(8, 512, 2), dim3(256), 0, stream, xT, pwih0, bias0, xgb);
  hipLaunchKernelGGL((lstm_rec<0>), dim3(8), dim3(512), 0, stream, xgb, pwhh0, o1, out, hx, ctr);
  hipLaunchKernelGGL((gemm_xg<512>), dim3(8, 512, 2), dim3(256), 0, stream, o1, pwih1, bias1, xgb);
  hipLaunchKernelGGL((lstm_rec<1>), dim3(8), dim3(512), 0, stream, xgb, pwhh1, (_Float16*)nullptr, out, hx, ctr);
}